// Round 3
// baseline (9493.723 us; speedup 1.0000x reference)
//
#include <hip/hip_runtime.h>
#include <hip/hip_bf16.h>
#include <math.h>

#define BQ   512   // batch
#define EDIM 512
#define HDIM 1024
#define VDIM 1024
#define TLEN 32
#define TOUT 33

// ---------------------------------------------------------------------------
// Static device workspace (22 MB) — write-before-read each call.
// ---------------------------------------------------------------------------
__device__ float g_cur[BQ * EDIM];
__device__ float g_h0[BQ * HDIM];
__device__ float g_c0[BQ * HDIM];
__device__ float g_h1[BQ * HDIM];
__device__ float g_c1[BQ * HDIM];
__device__ float g_hn[BQ * HDIM];
__device__ float g_gates[BQ * 4 * HDIM];
__device__ float g_logits[BQ * VDIM];

// ---------------------------------------------------------------------------
// init: zero h0,c0,h1,c1 + zero column t=32 of all three fp32 outputs
// ---------------------------------------------------------------------------
__global__ void init_kernel(float* __restrict__ out) {
    int i = blockIdx.x * 256 + threadIdx.x;   // [0, BQ*HDIM)
    g_h0[i] = 0.f; g_c0[i] = 0.f; g_h1[i] = 0.f; g_c1[i] = 0.f;
    if (i < 3 * BQ) {
        int which = i / BQ, b = i % BQ;
        out[(size_t)which * BQ * TOUT + (size_t)b * TOUT + (TOUT - 1)] = 0.f;
    }
}

// ---------------------------------------------------------------------------
// fp32 GEMM body: out[M,N] = A1[M,K1]@W1[N,K1]^T + A2[M,K2]@W2[N,K2]^T + b1 + b2
// 64x64 tile, 256 threads, 4x4 per thread, K-tile 16, LDS pad to 68 floats.
// ---------------------------------------------------------------------------
#define GBM 64
#define GBN 64
#define GBK 16
#define GPAD 68

__device__ __forceinline__ void gemm2_body(
    const float* __restrict__ A1, int K1, const float* __restrict__ W1,
    const float* __restrict__ A2, int K2, const float* __restrict__ W2,
    const float* __restrict__ b1, const float* __restrict__ b2,
    float* __restrict__ out, int N)
{
    __shared__ __align__(16) float As[GBK][GPAD];
    __shared__ __align__(16) float Bs[GBK][GPAD];
    int tid = threadIdx.x;
    int tx = tid & 15, ty = tid >> 4;
    int m0 = blockIdx.y * GBM, n0 = blockIdx.x * GBN;
    int lm = tid >> 2;          // 0..63: row within tile
    int lk = (tid & 3) << 2;    // 0,4,8,12: k-quad
    float acc[4][4] = {};

    for (int phase = 0; phase < 2; ++phase) {
        const float* A = phase ? A2 : A1;
        const float* W = phase ? W2 : W1;
        int K = phase ? K2 : K1;
        if (K == 0) continue;
        for (int k0 = 0; k0 < K; k0 += GBK) {
            float4 av = *(const float4*)(A + (size_t)(m0 + lm) * K + k0 + lk);
            float4 wv = *(const float4*)(W + (size_t)(n0 + lm) * K + k0 + lk);
            As[lk + 0][lm] = av.x; As[lk + 1][lm] = av.y;
            As[lk + 2][lm] = av.z; As[lk + 3][lm] = av.w;
            Bs[lk + 0][lm] = wv.x; Bs[lk + 1][lm] = wv.y;
            Bs[lk + 2][lm] = wv.z; Bs[lk + 3][lm] = wv.w;
            __syncthreads();
            #pragma unroll
            for (int kk = 0; kk < GBK; ++kk) {
                float4 a  = *(const float4*)&As[kk][ty * 4];
                float4 bq = *(const float4*)&Bs[kk][tx * 4];
                float aa[4] = {a.x, a.y, a.z, a.w};
                float bb[4] = {bq.x, bq.y, bq.z, bq.w};
                #pragma unroll
                for (int i = 0; i < 4; ++i)
                    #pragma unroll
                    for (int j = 0; j < 4; ++j)
                        acc[i][j] = fmaf(aa[i], bb[j], acc[i][j]);
            }
            __syncthreads();
        }
    }
    #pragma unroll
    for (int i = 0; i < 4; ++i) {
        int m = m0 + ty * 4 + i;
        #pragma unroll
        for (int j = 0; j < 4; ++j) {
            int n = n0 + tx * 4 + j;
            float v = acc[i][j];
            if (b1) v += b1[n];
            if (b2) v += b2[n];
            out[(size_t)m * N + n] = v;
        }
    }
}

// Wrappers binding specific static buffers (weights stay kernel args).
__global__ __launch_bounds__(256) void gemm_in(const float* __restrict__ x,
                                               const float* __restrict__ w_in,
                                               const float* __restrict__ b_in) {
    gemm2_body(x, 64, w_in, nullptr, 0, nullptr, b_in, nullptr, g_cur, EDIM);
}
__global__ __launch_bounds__(256) void gemm_g0(const float* __restrict__ w_ih0,
                                               const float* __restrict__ w_hh0,
                                               const float* __restrict__ b_ih0,
                                               const float* __restrict__ b_hh0) {
    gemm2_body(g_cur, EDIM, w_ih0, g_h0, HDIM, w_hh0, b_ih0, b_hh0, g_gates, 4 * HDIM);
}
__global__ __launch_bounds__(256) void gemm_g1(const float* __restrict__ w_ih1,
                                               const float* __restrict__ w_hh1,
                                               const float* __restrict__ b_ih1,
                                               const float* __restrict__ b_hh1) {
    gemm2_body(g_h0, HDIM, w_ih1, g_h1, HDIM, w_hh1, b_ih1, b_hh1, g_gates, 4 * HDIM);
}
__global__ __launch_bounds__(256) void gemm_lg(const float* __restrict__ w_out,
                                               const float* __restrict__ b_out) {
    gemm2_body(g_hn, HDIM, w_out, nullptr, 0, nullptr, b_out, nullptr, g_logits, VDIM);
}

// ---------------------------------------------------------------------------
// LSTM cell 0 elementwise: gates [B,4H] (i,f,g,o) -> h0,c0
// ---------------------------------------------------------------------------
__global__ void lstm0_kernel() {
    int i = blockIdx.x * 256 + threadIdx.x;          // [0, B*H)
    int b = i >> 10, j = i & 1023;
    const float* g = g_gates + (size_t)b * 4 * HDIM;
    float I = 1.f / (1.f + expf(-g[j]));
    float F = 1.f / (1.f + expf(-g[j + HDIM]));
    float G = tanhf(g[j + 2 * HDIM]);
    float O = 1.f / (1.f + expf(-g[j + 3 * HDIM]));
    float c = F * g_c0[i] + I * G;
    float h = O * tanhf(c);
    g_c0[i] = c;
    g_h0[i] = h;
}

// ---------------------------------------------------------------------------
// LSTM cell 1 + LayerNorm: one block per batch row (256 thr x 4 elems)
// ---------------------------------------------------------------------------
__global__ __launch_bounds__(256) void lstm1_ln_kernel(const float* __restrict__ ln_g,
                                                       const float* __restrict__ ln_b) {
    __shared__ float sbuf[4];
    int b = blockIdx.x, tid = threadIdx.x;
    int lane = tid & 63, wid = tid >> 6;
    const float* g = g_gates + (size_t)b * 4 * HDIM;
    float hv[4];
    float sum = 0.f;
    #pragma unroll
    for (int r = 0; r < 4; ++r) {
        int j = tid + 256 * r;
        float I = 1.f / (1.f + expf(-g[j]));
        float F = 1.f / (1.f + expf(-g[j + HDIM]));
        float G = tanhf(g[j + 2 * HDIM]);
        float O = 1.f / (1.f + expf(-g[j + 3 * HDIM]));
        float c = F * g_c1[(size_t)b * HDIM + j] + I * G;
        float h = O * tanhf(c);
        g_c1[(size_t)b * HDIM + j] = c;
        g_h1[(size_t)b * HDIM + j] = h;
        hv[r] = h;
        sum += h;
    }
    for (int off = 32; off > 0; off >>= 1) sum += __shfl_down(sum, off, 64);
    if (lane == 0) sbuf[wid] = sum;
    __syncthreads();
    float mu = (sbuf[0] + sbuf[1] + sbuf[2] + sbuf[3]) * (1.f / HDIM);
    __syncthreads();
    float sq = 0.f;
    #pragma unroll
    for (int r = 0; r < 4; ++r) { float d = hv[r] - mu; sq += d * d; }
    for (int off = 32; off > 0; off >>= 1) sq += __shfl_down(sq, off, 64);
    if (lane == 0) sbuf[wid] = sq;
    __syncthreads();
    float var = (sbuf[0] + sbuf[1] + sbuf[2] + sbuf[3]) * (1.f / HDIM);
    float rstd = 1.f / sqrtf(var + 1e-5f);
    #pragma unroll
    for (int r = 0; r < 4; ++r) {
        int j = tid + 256 * r;
        g_hn[(size_t)b * HDIM + j] = (hv[r] - mu) * rstd * ln_g[j] + ln_b[j];
    }
}

// ---------------------------------------------------------------------------
// per-row: log_softmax -> argmax(first-index), logprob=-logZ, entropy;
// fp32 outputs at [b][t], next input g_cur[b] = emb[sym]
// ---------------------------------------------------------------------------
__global__ __launch_bounds__(256) void softmax_row_kernel(
    const float* __restrict__ emb, float* __restrict__ out, int t)
{
    __shared__ float swv[4];
    __shared__ int   swi[4];
    __shared__ float sZ[4], sS[4];
    __shared__ float s_max;
    __shared__ int   s_idx;
    int b = blockIdx.x, tid = threadIdx.x;
    int lane = tid & 63, wid = tid >> 6;
    const float* x = g_logits + (size_t)b * VDIM;
    float4 xv = ((const float4*)x)[tid];   // j = 4*tid..4*tid+3

    // max + first-index argmax
    float mv = xv.x; int mi = 4 * tid;
    if (xv.y > mv) { mv = xv.y; mi = 4 * tid + 1; }
    if (xv.z > mv) { mv = xv.z; mi = 4 * tid + 2; }
    if (xv.w > mv) { mv = xv.w; mi = 4 * tid + 3; }
    for (int off = 32; off > 0; off >>= 1) {
        float ov = __shfl_down(mv, off, 64);
        int   oi = __shfl_down(mi, off, 64);
        if (ov > mv || (ov == mv && oi < mi)) { mv = ov; mi = oi; }
    }
    if (lane == 0) { swv[wid] = mv; swi[wid] = mi; }
    __syncthreads();
    if (tid == 0) {
        mv = swv[0]; mi = swi[0];
        for (int w = 1; w < 4; ++w)
            if (swv[w] > mv || (swv[w] == mv && swi[w] < mi)) { mv = swv[w]; mi = swi[w]; }
        s_max = mv; s_idx = mi;
    }
    __syncthreads();
    float xmax = s_max;

    // Z = sum exp(s), S1 = sum exp(s)*s,  s = x - xmax
    float sv[4] = {xv.x - xmax, xv.y - xmax, xv.z - xmax, xv.w - xmax};
    float z = 0.f, s1 = 0.f;
    #pragma unroll
    for (int r = 0; r < 4; ++r) { float e = expf(sv[r]); z += e; s1 += e * sv[r]; }
    for (int off = 32; off > 0; off >>= 1) {
        z  += __shfl_down(z, off, 64);
        s1 += __shfl_down(s1, off, 64);
    }
    if (lane == 0) { sZ[wid] = z; sS[wid] = s1; }
    __syncthreads();
    if (tid == 0) {
        float Z = sZ[0] + sZ[1] + sZ[2] + sZ[3];
        float S1 = sS[0] + sS[1] + sS[2] + sS[3];
        float logZ = logf(Z);
        float ent = logZ - S1 / Z;
        out[(size_t)b * TOUT + t]                         = (float)s_idx;
        out[(size_t)BQ * TOUT + (size_t)b * TOUT + t]     = -logZ;
        out[(size_t)2 * BQ * TOUT + (size_t)b * TOUT + t] = ent;
    }
    __syncthreads();
    int sym = s_idx;
    const float* e = emb + (size_t)sym * EDIM;
    for (int j = tid; j < EDIM; j += 256)
        g_cur[(size_t)b * EDIM + j] = e[j];
}

// ---------------------------------------------------------------------------
extern "C" void kernel_launch(void* const* d_in, const int* in_sizes, int n_in,
                              void* d_out, int out_size, void* d_ws, size_t ws_size,
                              hipStream_t stream) {
    const float* x     = (const float*)d_in[0];
    const float* w_in  = (const float*)d_in[1];
    const float* b_in  = (const float*)d_in[2];
    const float* w_ih0 = (const float*)d_in[3];
    const float* w_hh0 = (const float*)d_in[4];
    const float* b_ih0 = (const float*)d_in[5];
    const float* b_hh0 = (const float*)d_in[6];
    const float* w_ih1 = (const float*)d_in[7];
    const float* w_hh1 = (const float*)d_in[8];
    const float* b_ih1 = (const float*)d_in[9];
    const float* b_hh1 = (const float*)d_in[10];
    const float* ln_g  = (const float*)d_in[11];
    const float* ln_b  = (const float*)d_in[12];
    const float* w_out = (const float*)d_in[13];
    const float* b_out = (const float*)d_in[14];
    const float* emb   = (const float*)d_in[15];
    float* out = (float*)d_out;

    // zero states + zero-column of outputs
    init_kernel<<<(BQ * HDIM) / 256, 256, 0, stream>>>(out);

    // inp = x @ w_in^T + b_in  -> g_cur [512,512]
    gemm_in<<<dim3(EDIM / GBN, BQ / GBM), 256, 0, stream>>>(x, w_in, b_in);

    for (int t = 0; t < TLEN; ++t) {
        gemm_g0<<<dim3(4 * HDIM / GBN, BQ / GBM), 256, 0, stream>>>(w_ih0, w_hh0, b_ih0, b_hh0);
        lstm0_kernel<<<(BQ * HDIM) / 256, 256, 0, stream>>>();

        gemm_g1<<<dim3(4 * HDIM / GBN, BQ / GBM), 256, 0, stream>>>(w_ih1, w_hh1, b_ih1, b_hh1);
        lstm1_ln_kernel<<<BQ, 256, 0, stream>>>(ln_g, ln_b);

        gemm_lg<<<dim3(VDIM / GBN, BQ / GBM), 256, 0, stream>>>(w_out, b_out);

        softmax_row_kernel<<<BQ, 256, 0, stream>>>(emb, out, t);
    }
}

// Round 4
// 4206.591 us; speedup vs baseline: 2.2569x; 2.2569x over previous
//
#include <hip/hip_runtime.h>
#include <hip/hip_bf16.h>
#include <math.h>

#define BQ   512
#define EDIM 512
#define HDIM 1024
#define VDIM 1024
#define TLEN 32
#define TOUT 33
#define PGS  (BQ * 4 * HDIM)   // part_g plane stride (512*4096)
#define PLS  (BQ * VDIM)       // part_lg plane stride (512*1024)

typedef _Float16 half8  __attribute__((ext_vector_type(8)));
typedef _Float16 half4v __attribute__((ext_vector_type(4)));
typedef float    f32x16 __attribute__((ext_vector_type(16)));

#define GLOAD_LDS16(gp, lp) __builtin_amdgcn_global_load_lds( \
    (const __attribute__((address_space(1))) void*)(gp),      \
    (__attribute__((address_space(3))) void*)(lp), 16, 0, 0)

// ---------------------------------------------------------------------------
// Static device buffers (~95MB bss) — every buffer write-before-read per call.
// f16 split planes: value = hi + lo/4096 (lo pre-scaled by 2^12, no subnormals)
// ---------------------------------------------------------------------------
__device__ _Float16 g_curh[BQ*EDIM], g_curl[BQ*EDIM];
__device__ _Float16 g_h0h[BQ*HDIM], g_h0l[BQ*HDIM];
__device__ _Float16 g_h1h[BQ*HDIM], g_h1l[BQ*HDIM];
__device__ _Float16 g_hnh[BQ*HDIM], g_hnl[BQ*HDIM];
__device__ float    g_c0[BQ*HDIM], g_c1[BQ*HDIM];

__device__ _Float16 g_wih0h[4*HDIM*EDIM], g_wih0l[4*HDIM*EDIM];
__device__ _Float16 g_whh0h[4*HDIM*HDIM], g_whh0l[4*HDIM*HDIM];
__device__ _Float16 g_wih1h[4*HDIM*HDIM], g_wih1l[4*HDIM*HDIM];
__device__ _Float16 g_whh1h[4*HDIM*HDIM], g_whh1l[4*HDIM*HDIM];
__device__ _Float16 g_wouth[VDIM*HDIM],   g_woutl[VDIM*HDIM];

__device__ float g_part_g[2*PGS];    // split-K partials for gate GEMMs (S=2)
__device__ float g_part_lg[4*PLS];   // split-K partials for logits GEMM (S=4)

// ---------------------------------------------------------------------------
// init: zero states + t=32 column of outputs
// ---------------------------------------------------------------------------
__global__ void init_kernel(float* __restrict__ out) {
    int i = blockIdx.x * 256 + threadIdx.x;   // [0, BQ*HDIM)
    g_c0[i] = 0.f; g_c1[i] = 0.f;
    g_h0h[i] = (_Float16)0.f; g_h0l[i] = (_Float16)0.f;
    g_h1h[i] = (_Float16)0.f; g_h1l[i] = (_Float16)0.f;
    if (i < 3 * BQ) {
        int which = i / BQ, b = i % BQ;
        out[(size_t)which * BQ * TOUT + (size_t)b * TOUT + (TOUT - 1)] = 0.f;
    }
}

// ---------------------------------------------------------------------------
// fp32 -> (hi, lo*2^12) fp16 split, 4 elems/thread
// ---------------------------------------------------------------------------
__global__ void split_kernel(const float* __restrict__ w, _Float16* __restrict__ hi,
                             _Float16* __restrict__ lo, int nquads) {
    int q = blockIdx.x * 256 + threadIdx.x;
    if (q >= nquads) return;
    float4 v = ((const float4*)w)[q];
    half4v h, l;
    h[0] = (_Float16)v.x; l[0] = (_Float16)((v.x - (float)h[0]) * 4096.f);
    h[1] = (_Float16)v.y; l[1] = (_Float16)((v.y - (float)h[1]) * 4096.f);
    h[2] = (_Float16)v.z; l[2] = (_Float16)((v.z - (float)h[2]) * 4096.f);
    h[3] = (_Float16)v.w; l[3] = (_Float16)((v.w - (float)h[3]) * 4096.f);
    ((half4v*)hi)[q] = h;
    ((half4v*)lo)[q] = l;
}

__device__ __forceinline__ void split1(float x, _Float16* hp, _Float16* lp) {
    _Float16 h = (_Float16)x;
    *hp = h;
    *lp = (_Float16)((x - (float)h) * 4096.f);
}

// ---------------------------------------------------------------------------
// MFMA GEMM: out_part[s] = A@W^T over this block's K-chunk.
// A = Ah + Al/4096, W = Wh + Wl/4096 (f16 planes, row-major [rows][K]).
// Tile 64x128, 4 waves (wave w owns n-strip w*32), 2 M-frags of 32x32x16.
// Split-K: blockIdx.z = s in [0,S); each source's K divided by S.
// Products: hh -> accM;  h*l and l*h -> accL (2^12-scaled); out = accM+accL/4096
// ---------------------------------------------------------------------------
__global__ __launch_bounds__(256) void gemm_mfma(
    const _Float16* __restrict__ Ah1, const _Float16* __restrict__ Al1, int K1,
    const _Float16* __restrict__ Wh1, const _Float16* __restrict__ Wl1,
    const _Float16* __restrict__ Ah2, const _Float16* __restrict__ Al2, int K2,
    const _Float16* __restrict__ Wh2, const _Float16* __restrict__ Wl2,
    float* __restrict__ outp, int N, int S)
{
    __shared__ __align__(16) _Float16 sAh[64*32];
    __shared__ __align__(16) _Float16 sAl[64*32];
    __shared__ __align__(16) _Float16 sBh[128*32];
    __shared__ __align__(16) _Float16 sBl[128*32];
    int tid = threadIdx.x;
    int l = tid & 63, w = tid >> 6;
    int n0 = blockIdx.x * 128, m0 = blockIdx.y * 64, s = blockIdx.z;

    f32x16 accM0 = {}, accM1 = {}, accL0 = {}, accL1 = {};

    for (int src = 0; src < 2; ++src) {
        const _Float16* Ah = src ? Ah2 : Ah1;
        const _Float16* Al = src ? Al2 : Al1;
        const _Float16* Wh = src ? Wh2 : Wh1;
        const _Float16* Wl = src ? Wl2 : Wl1;
        int K = src ? K2 : K1;
        if (K == 0) continue;
        int kchunk = K / S;
        int kbeg = s * kchunk, kend = kbeg + kchunk;
        for (int k0 = kbeg; k0 < kend; k0 += 32) {
            // stage BK=32 tiles: 24 gload16 instrs total, 6 per wave
            #pragma unroll
            for (int qq = 0; qq < 6; ++qq) {
                int q = w * 6 + qq;          // wave-uniform
                const _Float16* sp; _Float16* dp; int rowbase, j;
                if (q < 4)       { sp = Ah; dp = sAh; j = q;      rowbase = m0; }
                else if (q < 8)  { sp = Al; dp = sAl; j = q - 4;  rowbase = m0; }
                else if (q < 16) { sp = Wh; dp = sBh; j = q - 8;  rowbase = n0; }
                else             { sp = Wl; dp = sBl; j = q - 16; rowbase = n0; }
                int slot = j * 64 + l;
                int row = slot >> 2, kq = slot & 3;   // 4x16B slots per 64B row
                const _Float16* gp = sp + (size_t)(rowbase + row) * K + k0 + kq * 8;
                GLOAD_LDS16(gp, dp + j * 512);        // dest: uniform base + lane*16
            }
            __syncthreads();   // drains vmcnt for global_load_lds
            #pragma unroll
            for (int kh = 0; kh < 2; ++kh) {
                int koff = (l >> 5) * 8 + kh * 16;    // lane's 8 contiguous k
                half8 ah0 = *(const half8*)&sAh[((l & 31)) * 32 + koff];
                half8 ah1 = *(const half8*)&sAh[((l & 31) + 32) * 32 + koff];
                half8 al0 = *(const half8*)&sAl[((l & 31)) * 32 + koff];
                half8 al1 = *(const half8*)&sAl[((l & 31) + 32) * 32 + koff];
                half8 bh  = *(const half8*)&sBh[(w * 32 + (l & 31)) * 32 + koff];
                half8 bl  = *(const half8*)&sBl[(w * 32 + (l & 31)) * 32 + koff];
                accM0 = __builtin_amdgcn_mfma_f32_32x32x16_f16(ah0, bh, accM0, 0, 0, 0);
                accM1 = __builtin_amdgcn_mfma_f32_32x32x16_f16(ah1, bh, accM1, 0, 0, 0);
                accL0 = __builtin_amdgcn_mfma_f32_32x32x16_f16(ah0, bl, accL0, 0, 0, 0);
                accL1 = __builtin_amdgcn_mfma_f32_32x32x16_f16(ah1, bl, accL1, 0, 0, 0);
                accL0 = __builtin_amdgcn_mfma_f32_32x32x16_f16(al0, bh, accL0, 0, 0, 0);
                accL1 = __builtin_amdgcn_mfma_f32_32x32x16_f16(al1, bh, accL1, 0, 0, 0);
            }
            __syncthreads();
        }
    }
    // epilogue: partial plane s; C/D layout: n = l&31, m = (r&3)+8*(r>>2)+4*(l>>5)
    float* op = outp + (size_t)s * BQ * N;
    int n = n0 + w * 32 + (l & 31);
    #pragma unroll
    for (int r = 0; r < 16; ++r) {
        int row = (r & 3) + 8 * (r >> 2) + 4 * (l >> 5);
        op[(size_t)(m0 + row) * N + n]      = accM0[r] + accL0[r] * (1.f / 4096.f);
        op[(size_t)(m0 + 32 + row) * N + n] = accM1[r] + accL1[r] * (1.f / 4096.f);
    }
}

// ---------------------------------------------------------------------------
// fp32 GEMM for inp = x @ w_in^T + b_in (runs once, K=64); writes split planes
// ---------------------------------------------------------------------------
#define GBK 16
#define GPAD 68
__global__ __launch_bounds__(256) void gemm_in(const float* __restrict__ x,
                                               const float* __restrict__ w_in,
                                               const float* __restrict__ b_in) {
    __shared__ __align__(16) float As[GBK][GPAD];
    __shared__ __align__(16) float Bs[GBK][GPAD];
    int tid = threadIdx.x;
    int tx = tid & 15, ty = tid >> 4;
    int m0 = blockIdx.y * 64, n0 = blockIdx.x * 64;
    int lm = tid >> 2, lk = (tid & 3) << 2;
    const int K = 64, N = EDIM;
    float acc[4][4] = {};
    for (int k0 = 0; k0 < K; k0 += GBK) {
        float4 av = *(const float4*)(x + (size_t)(m0 + lm) * K + k0 + lk);
        float4 wv = *(const float4*)(w_in + (size_t)(n0 + lm) * K + k0 + lk);
        As[lk + 0][lm] = av.x; As[lk + 1][lm] = av.y;
        As[lk + 2][lm] = av.z; As[lk + 3][lm] = av.w;
        Bs[lk + 0][lm] = wv.x; Bs[lk + 1][lm] = wv.y;
        Bs[lk + 2][lm] = wv.z; Bs[lk + 3][lm] = wv.w;
        __syncthreads();
        #pragma unroll
        for (int kk = 0; kk < GBK; ++kk) {
            float4 a  = *(const float4*)&As[kk][ty * 4];
            float4 bq = *(const float4*)&Bs[kk][tx * 4];
            float aa[4] = {a.x, a.y, a.z, a.w};
            float bb[4] = {bq.x, bq.y, bq.z, bq.w};
            #pragma unroll
            for (int i = 0; i < 4; ++i)
                #pragma unroll
                for (int j = 0; j < 4; ++j)
                    acc[i][j] = fmaf(aa[i], bb[j], acc[i][j]);
        }
        __syncthreads();
    }
    #pragma unroll
    for (int i = 0; i < 4; ++i) {
        int m = m0 + ty * 4 + i;
        #pragma unroll
        for (int j = 0; j < 4; ++j) {
            int n = n0 + tx * 4 + j;
            float v = acc[i][j] + b_in[n];
            split1(v, &g_curh[(size_t)m * N + n], &g_curl[(size_t)m * N + n]);
        }
    }
}

__device__ __forceinline__ float sigm(float x) { return 1.f / (1.f + expf(-x)); }

// ---------------------------------------------------------------------------
// LSTM cell 0: gates = part0+part1+b_ih+b_hh -> h0 (split planes), c0
// 4 elems/thread
// ---------------------------------------------------------------------------
__global__ void lstm0_kernel(const float* __restrict__ bi, const float* __restrict__ bh) {
    int qidx = blockIdx.x * 256 + threadIdx.x;   // quad index over B*H/4
    int b = qidx >> 8;                           // 256 quads per row
    int j = (qidx & 255) * 4;
    size_t base = (size_t)b * 4096;
    float4 G[4];
    #pragma unroll
    for (int g = 0; g < 4; ++g) {
        float4 p0 = *(const float4*)&g_part_g[base + g * 1024 + j];
        float4 p1 = *(const float4*)&g_part_g[PGS + base + g * 1024 + j];
        float4 b0 = *(const float4*)&bi[g * 1024 + j];
        float4 b1 = *(const float4*)&bh[g * 1024 + j];
        G[g].x = p0.x + p1.x + b0.x + b1.x;
        G[g].y = p0.y + p1.y + b0.y + b1.y;
        G[g].z = p0.z + p1.z + b0.z + b1.z;
        G[g].w = p0.w + p1.w + b0.w + b1.w;
    }
    size_t hb = (size_t)b * HDIM + j;
    float4 cin = *(const float4*)&g_c0[hb];
    float c[4], h[4];
    float ci[4] = {cin.x, cin.y, cin.z, cin.w};
    float gi[4] = {G[0].x, G[0].y, G[0].z, G[0].w};
    float gf[4] = {G[1].x, G[1].y, G[1].z, G[1].w};
    float gg[4] = {G[2].x, G[2].y, G[2].z, G[2].w};
    float go[4] = {G[3].x, G[3].y, G[3].z, G[3].w};
    half4v hh, hl;
    #pragma unroll
    for (int r = 0; r < 4; ++r) {
        c[r] = sigm(gf[r]) * ci[r] + sigm(gi[r]) * tanhf(gg[r]);
        h[r] = sigm(go[r]) * tanhf(c[r]);
        _Float16 hi16 = (_Float16)h[r];
        hh[r] = hi16;
        hl[r] = (_Float16)((h[r] - (float)hi16) * 4096.f);
    }
    *(float4*)&g_c0[hb] = {c[0], c[1], c[2], c[3]};
    *(half4v*)&g_h0h[hb] = hh;
    *(half4v*)&g_h0l[hb] = hl;
}

// ---------------------------------------------------------------------------
// LSTM cell 1 + LayerNorm: one block per row; 4 elems/thread (quad j=4*tid)
// writes c1, h1 split planes, hn split planes
// ---------------------------------------------------------------------------
__global__ __launch_bounds__(256) void lstm1_ln_kernel(
    const float* __restrict__ bi, const float* __restrict__ bh,
    const float* __restrict__ ln_g, const float* __restrict__ ln_b)
{
    __shared__ float sbuf[4];
    int b = blockIdx.x, tid = threadIdx.x;
    int lane = tid & 63, wid = tid >> 6;
    int j = tid * 4;
    size_t base = (size_t)b * 4096;
    float4 G[4];
    #pragma unroll
    for (int g = 0; g < 4; ++g) {
        float4 p0 = *(const float4*)&g_part_g[base + g * 1024 + j];
        float4 p1 = *(const float4*)&g_part_g[PGS + base + g * 1024 + j];
        float4 b0 = *(const float4*)&bi[g * 1024 + j];
        float4 b1 = *(const float4*)&bh[g * 1024 + j];
        G[g].x = p0.x + p1.x + b0.x + b1.x;
        G[g].y = p0.y + p1.y + b0.y + b1.y;
        G[g].z = p0.z + p1.z + b0.z + b1.z;
        G[g].w = p0.w + p1.w + b0.w + b1.w;
    }
    size_t hb = (size_t)b * HDIM + j;
    float4 cin = *(const float4*)&g_c1[hb];
    float ci[4] = {cin.x, cin.y, cin.z, cin.w};
    float gi[4] = {G[0].x, G[0].y, G[0].z, G[0].w};
    float gf[4] = {G[1].x, G[1].y, G[1].z, G[1].w};
    float gg[4] = {G[2].x, G[2].y, G[2].z, G[2].w};
    float go[4] = {G[3].x, G[3].y, G[3].z, G[3].w};
    float c[4], h[4];
    float sum = 0.f;
    #pragma unroll
    for (int r = 0; r < 4; ++r) {
        c[r] = sigm(gf[r]) * ci[r] + sigm(gi[r]) * tanhf(gg[r]);
        h[r] = sigm(go[r]) * tanhf(c[r]);
        sum += h[r];
    }
    *(float4*)&g_c1[hb] = {c[0], c[1], c[2], c[3]};
    half4v h1h, h1l;
    #pragma unroll
    for (int r = 0; r < 4; ++r) {
        _Float16 hi16 = (_Float16)h[r];
        h1h[r] = hi16;
        h1l[r] = (_Float16)((h[r] - (float)hi16) * 4096.f);
    }
    *(half4v*)&g_h1h[hb] = h1h;
    *(half4v*)&g_h1l[hb] = h1l;

    for (int off = 32; off > 0; off >>= 1) sum += __shfl_down(sum, off, 64);
    if (lane == 0) sbuf[wid] = sum;
    __syncthreads();
    float mu = (sbuf[0] + sbuf[1] + sbuf[2] + sbuf[3]) * (1.f / HDIM);
    __syncthreads();
    float sq = 0.f;
    #pragma unroll
    for (int r = 0; r < 4; ++r) { float d = h[r] - mu; sq += d * d; }
    for (int off = 32; off > 0; off >>= 1) sq += __shfl_down(sq, off, 64);
    if (lane == 0) sbuf[wid] = sq;
    __syncthreads();
    float var = (sbuf[0] + sbuf[1] + sbuf[2] + sbuf[3]) * (1.f / HDIM);
    float rstd = 1.f / sqrtf(var + 1e-5f);
    half4v nh, nl;
    #pragma unroll
    for (int r = 0; r < 4; ++r) {
        float hn = (h[r] - mu) * rstd * ln_g[j + r] + ln_b[j + r];
        _Float16 hi16 = (_Float16)hn;
        nh[r] = hi16;
        nl[r] = (_Float16)((hn - (float)hi16) * 4096.f);
    }
    *(half4v*)&g_hnh[hb] = nh;
    *(half4v*)&g_hnl[hb] = nl;
}

// ---------------------------------------------------------------------------
// per-row softmax: logits = sum of 4 part planes + b_out; argmax/logprob/ent;
// next input cur = emb[sym] (split planes)
// ---------------------------------------------------------------------------
__global__ __launch_bounds__(256) void softmax_row_kernel(
    const float* __restrict__ b_out, const float* __restrict__ emb,
    float* __restrict__ out, int t)
{
    __shared__ float swv[4];
    __shared__ int   swi[4];
    __shared__ float sZ[4], sS[4];
    __shared__ float s_max;
    __shared__ int   s_idx;
    int b = blockIdx.x, tid = threadIdx.x;
    int lane = tid & 63, wid = tid >> 6;
    size_t base = (size_t)b * VDIM + 4 * tid;
    float4 xv = *(const float4*)&b_out[4 * tid];
    #pragma unroll
    for (int s = 0; s < 4; ++s) {
        float4 p = *(const float4*)&g_part_lg[(size_t)s * PLS + base];
        xv.x += p.x; xv.y += p.y; xv.z += p.z; xv.w += p.w;
    }

    float mv = xv.x; int mi = 4 * tid;
    if (xv.y > mv) { mv = xv.y; mi = 4 * tid + 1; }
    if (xv.z > mv) { mv = xv.z; mi = 4 * tid + 2; }
    if (xv.w > mv) { mv = xv.w; mi = 4 * tid + 3; }
    for (int off = 32; off > 0; off >>= 1) {
        float ov = __shfl_down(mv, off, 64);
        int   oi = __shfl_down(mi, off, 64);
        if (ov > mv || (ov == mv && oi < mi)) { mv = ov; mi = oi; }
    }
    if (lane == 0) { swv[wid] = mv; swi[wid] = mi; }
    __syncthreads();
    if (tid == 0) {
        mv = swv[0]; mi = swi[0];
        for (int w = 1; w < 4; ++w)
            if (swv[w] > mv || (swv[w] == mv && swi[w] < mi)) { mv = swv[w]; mi = swi[w]; }
        s_max = mv; s_idx = mi;
    }
    __syncthreads();
    float xmax = s_max;

    float sv[4] = {xv.x - xmax, xv.y - xmax, xv.z - xmax, xv.w - xmax};
    float z = 0.f, s1 = 0.f;
    #pragma unroll
    for (int r = 0; r < 4; ++r) { float e = expf(sv[r]); z += e; s1 += e * sv[r]; }
    for (int off = 32; off > 0; off >>= 1) {
        z  += __shfl_down(z, off, 64);
        s1 += __shfl_down(s1, off, 64);
    }
    if (lane == 0) { sZ[wid] = z; sS[wid] = s1; }
    __syncthreads();
    if (tid == 0) {
        float Z = sZ[0] + sZ[1] + sZ[2] + sZ[3];
        float S1 = sS[0] + sS[1] + sS[2] + sS[3];
        float logZ = logf(Z);
        float ent = logZ - S1 / Z;
        out[(size_t)b * TOUT + t]                         = (float)s_idx;
        out[(size_t)BQ * TOUT + (size_t)b * TOUT + t]     = -logZ;
        out[(size_t)2 * BQ * TOUT + (size_t)b * TOUT + t] = ent;
    }
    __syncthreads();
    int sym = s_idx;
    const float* e = emb + (size_t)sym * EDIM;
    for (int j = tid; j < EDIM; j += 256) {
        split1(e[j], &g_curh[(size_t)b * EDIM + j], &g_curl[(size_t)b * EDIM + j]);
    }
}

// ---------------------------------------------------------------------------
extern "C" void kernel_launch(void* const* d_in, const int* in_sizes, int n_in,
                              void* d_out, int out_size, void* d_ws, size_t ws_size,
                              hipStream_t stream) {
    const float* x     = (const float*)d_in[0];
    const float* w_in  = (const float*)d_in[1];
    const float* b_in  = (const float*)d_in[2];
    const float* w_ih0 = (const float*)d_in[3];
    const float* w_hh0 = (const float*)d_in[4];
    const float* b_ih0 = (const float*)d_in[5];
    const float* b_hh0 = (const float*)d_in[6];
    const float* w_ih1 = (const float*)d_in[7];
    const float* w_hh1 = (const float*)d_in[8];
    const float* b_ih1 = (const float*)d_in[9];
    const float* b_hh1 = (const float*)d_in[10];
    const float* ln_g  = (const float*)d_in[11];
    const float* ln_b  = (const float*)d_in[12];
    const float* w_out = (const float*)d_in[13];
    const float* b_out = (const float*)d_in[14];
    const float* emb   = (const float*)d_in[15];
    float* out = (float*)d_out;

    _Float16 *wih0h, *wih0l, *whh0h, *whh0l, *wih1h, *wih1l, *whh1h, *whh1l, *wouth, *woutl;
    hipGetSymbolAddress((void**)&wih0h, HIP_SYMBOL(g_wih0h));
    hipGetSymbolAddress((void**)&wih0l, HIP_SYMBOL(g_wih0l));
    hipGetSymbolAddress((void**)&whh0h, HIP_SYMBOL(g_whh0h));
    hipGetSymbolAddress((void**)&whh0l, HIP_SYMBOL(g_whh0l));
    hipGetSymbolAddress((void**)&wih1h, HIP_SYMBOL(g_wih1h));
    hipGetSymbolAddress((void**)&wih1l, HIP_SYMBOL(g_wih1l));
    hipGetSymbolAddress((void**)&whh1h, HIP_SYMBOL(g_whh1h));
    hipGetSymbolAddress((void**)&whh1l, HIP_SYMBOL(g_whh1l));
    hipGetSymbolAddress((void**)&wouth, HIP_SYMBOL(g_wouth));
    hipGetSymbolAddress((void**)&woutl, HIP_SYMBOL(g_woutl));
    _Float16 *curh, *curl, *h0h, *h0l, *h1h, *h1l, *hnh, *hnl;
    hipGetSymbolAddress((void**)&curh, HIP_SYMBOL(g_curh));
    hipGetSymbolAddress((void**)&curl, HIP_SYMBOL(g_curl));
    hipGetSymbolAddress((void**)&h0h, HIP_SYMBOL(g_h0h));
    hipGetSymbolAddress((void**)&h0l, HIP_SYMBOL(g_h0l));
    hipGetSymbolAddress((void**)&h1h, HIP_SYMBOL(g_h1h));
    hipGetSymbolAddress((void**)&h1l, HIP_SYMBOL(g_h1l));
    hipGetSymbolAddress((void**)&hnh, HIP_SYMBOL(g_hnh));
    hipGetSymbolAddress((void**)&hnl, HIP_SYMBOL(g_hnl));
    float *part_g, *part_lg;
    hipGetSymbolAddress((void**)&part_g, HIP_SYMBOL(g_part_g));
    hipGetSymbolAddress((void**)&part_lg, HIP_SYMBOL(g_part_lg));

    // init states + out tail column
    init_kernel<<<(BQ * HDIM) / 256, 256, 0, stream>>>(out);

    // one-time weight splits
    split_kernel<<<(4*HDIM*EDIM/4 + 255)/256, 256, 0, stream>>>(w_ih0, wih0h, wih0l, 4*HDIM*EDIM/4);
    split_kernel<<<(4*HDIM*HDIM/4 + 255)/256, 256, 0, stream>>>(w_hh0, whh0h, whh0l, 4*HDIM*HDIM/4);
    split_kernel<<<(4*HDIM*HDIM/4 + 255)/256, 256, 0, stream>>>(w_ih1, wih1h, wih1l, 4*HDIM*HDIM/4);
    split_kernel<<<(4*HDIM*HDIM/4 + 255)/256, 256, 0, stream>>>(w_hh1, whh1h, whh1l, 4*HDIM*HDIM/4);
    split_kernel<<<(VDIM*HDIM/4 + 255)/256, 256, 0, stream>>>(w_out, wouth, woutl, VDIM*HDIM/4);

    // inp = x @ w_in^T + b_in -> cur split planes
    gemm_in<<<dim3(EDIM / 64, BQ / 64), 256, 0, stream>>>(x, w_in, b_in);

    for (int t = 0; t < TLEN; ++t) {
        // gates0 = cur @ w_ih0^T + h0 @ w_hh0^T  (split-K S=2)
        gemm_mfma<<<dim3(4 * HDIM / 128, BQ / 64, 2), 256, 0, stream>>>(
            curh, curl, EDIM, wih0h, wih0l,
            h0h, h0l, HDIM, whh0h, whh0l,
            part_g, 4 * HDIM, 2);
        lstm0_kernel<<<(BQ * HDIM / 4) / 256, 256, 0, stream>>>(b_ih0, b_hh0);

        // gates1 = h0 @ w_ih1^T + h1 @ w_hh1^T  (split-K S=2)
        gemm_mfma<<<dim3(4 * HDIM / 128, BQ / 64, 2), 256, 0, stream>>>(
            h0h, h0l, HDIM, wih1h, wih1l,
            h1h, h1l, HDIM, whh1h, whh1l,
            part_g, 4 * HDIM, 2);
        lstm1_ln_kernel<<<BQ, 256, 0, stream>>>(b_ih1, b_hh1, ln_g, ln_b);

        // logits = hn @ w_out^T  (split-K S=4)
        gemm_mfma<<<dim3(VDIM / 128, BQ / 64, 4), 256, 0, stream>>>(
            hnh, hnl, HDIM, wouth, woutl,
            (const _Float16*)nullptr, (const _Float16*)nullptr, 0,
            (const _Float16*)nullptr, (const _Float16*)nullptr,
            part_lg, VDIM, 4);

        softmax_row_kernel<<<BQ, 256, 0, stream>>>(b_out, emb, out, t);
    }
}